// Round 2
// baseline (372.826 us; speedup 1.0000x reference)
//
#include <hip/hip_runtime.h>
#include <stdint.h>

// Problem constants
#define Nn 4
#define Cc 64
#define Hh 64
#define Ww 64
#define LL 4096   // H*W
#define KK 256    // feature dim: 64 channels * 4 causal taps
#define TRI 2080  // 64*65/2 upper-triangular 64x64 tile count per batch
#define BK 32
#define LDS_STRIDE 68  // 64 + 4 pad: keeps 16B alignment, breaks worst store conflicts

__device__ __forceinline__ unsigned f2ord(float f) {
    unsigned u = __float_as_uint(f);
    return u ^ ((u & 0x80000000u) ? 0xFFFFFFFFu : 0x80000000u);
}
__device__ __forceinline__ float ord2f(unsigned o) {
    unsigned u = (o & 0x80000000u) ? (o ^ 0x80000000u) : ~o;
    return __uint_as_float(u);
}

// Kernel 1: build normalized masked context vectors V[n][k][l], k = c*4 + tap.
// Taps (di,dj): (-1,-1), (-1,0), (-1,1), (0,-1). Zero outside image (padding).
__global__ __launch_bounds__(256) void build_v(const float* __restrict__ yhat,
                                               float* __restrict__ V) {
    int gid = blockIdx.x * 256 + threadIdx.x;
    int n = gid >> 12;
    int l = gid & (LL - 1);
    int y = l >> 6, x = l & 63;
    const float* src = yhat + (size_t)n * (Cc * LL);
    float sumsq = 0.f;
    for (int c = 0; c < Cc; ++c) {
        const float* p = src + c * LL;
        float t0 = (y > 0 && x > 0)  ? p[l - 65] : 0.f;
        float t1 = (y > 0)           ? p[l - 64] : 0.f;
        float t2 = (y > 0 && x < 63) ? p[l - 63] : 0.f;
        float t3 = (x > 0)           ? p[l - 1]  : 0.f;
        sumsq += t0 * t0 + t1 * t1 + t2 * t2 + t3 * t3;
    }
    float inv = 1.f / fmaxf(sqrtf(sumsq), 1e-12f);
    float* dst = V + (size_t)n * (KK * LL) + l;
    for (int c = 0; c < Cc; ++c) {
        const float* p = src + c * LL;
        float t0 = (y > 0 && x > 0)  ? p[l - 65] : 0.f;
        float t1 = (y > 0)           ? p[l - 64] : 0.f;
        float t2 = (y > 0 && x < 63) ? p[l - 63] : 0.f;
        float t3 = (x > 0)           ? p[l - 1]  : 0.f;
        dst[(size_t)(c * 4 + 0) * LL] = t0 * inv;
        dst[(size_t)(c * 4 + 1) * LL] = t1 * inv;
        dst[(size_t)(c * 4 + 2) * LL] = t2 * inv;
        dst[(size_t)(c * 4 + 3) * LL] = t3 * inv;
    }
}

// Kernel 2: triangular tiled "GEMM + column max" over R[l,m] = V_l . V_m, l < m.
// Per column m keep packed (ord(val)<<32)|(0xFFFFFFFF-l) via atomicMax.
__global__ __launch_bounds__(256) void simmax(const float* __restrict__ V,
                                              unsigned long long* __restrict__ best) {
    __shared__ float As[BK * LDS_STRIDE];
    __shared__ float Bs[BK * LDS_STRIDE];

    int bx = blockIdx.x;
    int n = bx / TRI;
    int t = bx % TRI;
    // decode triangular (i <= j): t = j*(j+1)/2 + i
    int j = (int)((sqrtf(8.f * (float)t + 1.f) - 1.f) * 0.5f);
    while ((j + 1) * (j + 2) / 2 <= t) ++j;
    while (j * (j + 1) / 2 > t) --j;
    int i = t - j * (j + 1) / 2;
    int l0 = i * 64, m0 = j * 64;

    const float* Vb = V + (size_t)n * (KK * LL);
    int tid = threadIdx.x;
    int lrow = tid >> 3;         // 0..31 (k within tile)
    int lcol = (tid & 7) * 8;    // 0..56 (position within tile, 8 floats/thread)

    int tr = tid & 15;           // row group (l)
    int tc = tid >> 4;           // col group (m)

    float acc[4][4] = {{0.f}};

    for (int k0 = 0; k0 < KK; k0 += BK) {
        const float* ga = Vb + (size_t)(k0 + lrow) * LL + l0 + lcol;
        const float* gb = Vb + (size_t)(k0 + lrow) * LL + m0 + lcol;
        float4 a0 = *(const float4*)ga;
        float4 a1 = *(const float4*)(ga + 4);
        float4 b0 = *(const float4*)gb;
        float4 b1 = *(const float4*)(gb + 4);
        __syncthreads();
        *(float4*)&As[lrow * LDS_STRIDE + lcol]     = a0;
        *(float4*)&As[lrow * LDS_STRIDE + lcol + 4] = a1;
        *(float4*)&Bs[lrow * LDS_STRIDE + lcol]     = b0;
        *(float4*)&Bs[lrow * LDS_STRIDE + lcol + 4] = b1;
        __syncthreads();
#pragma unroll
        for (int k = 0; k < BK; ++k) {
            float4 a = *(const float4*)&As[k * LDS_STRIDE + tr * 4];
            float4 b = *(const float4*)&Bs[k * LDS_STRIDE + tc * 4];
            float av[4] = {a.x, a.y, a.z, a.w};
            float bv[4] = {b.x, b.y, b.z, b.w};
#pragma unroll
            for (int r = 0; r < 4; ++r)
#pragma unroll
                for (int c2 = 0; c2 < 4; ++c2)
                    acc[r][c2] = fmaf(av[r], bv[c2], acc[r][c2]);
        }
    }

    unsigned long long* bb = best + (size_t)n * LL;
#pragma unroll
    for (int cc = 0; cc < 4; ++cc) {
        int m = m0 + tc * 4 + cc;
        unsigned long long key = 0ull;
#pragma unroll
        for (int rr = 0; rr < 4; ++rr) {
            int l = l0 + tr * 4 + rr;
            if (l < m) {
                unsigned long long k2 =
                    ((unsigned long long)f2ord(acc[rr][cc]) << 32) |
                    (unsigned long long)(0xFFFFFFFFu - (unsigned)l);
                key = (k2 > key) ? k2 : key;
            }
        }
        // reduce across the 16 tr-lanes (lane bits 0..3)
        for (int off = 1; off < 16; off <<= 1) {
            unsigned long long other = __shfl_xor(key, off, 64);
            key = (other > key) ? other : key;
        }
        if (tr == 0 && key != 0ull) atomicMax(bb + m, key);
    }
}

// Kernel 3: unpack best, write S, U, ref_unfold, arg with m==0 overrides.
// NOTE: the harness reads the ENTIRE concatenated output buffer as float32,
// so arg must be written as float VALUES (e.g. -1.0f), not int32 bit patterns.
__global__ __launch_bounds__(256) void writeout(const float* __restrict__ yhat,
                                                const float* __restrict__ yprob,
                                                const unsigned long long* __restrict__ best,
                                                float* __restrict__ out) {
    int bx = blockIdx.x;   // n*64 + mb
    int n = bx >> 6;
    int mb = bx & 63;
    int tid = threadIdx.x;
    int mm = tid & 63;
    int fq = tid >> 6;     // 0..3
    int m = mb * 64 + mm;

    unsigned long long key = best[(size_t)n * LL + m];
    unsigned l = 0xFFFFFFFFu - (unsigned)(key & 0xFFFFFFFFull);
    float val = ord2f((unsigned)(key >> 32));
    bool zero = (m == 0);
    if (zero) l = 0;
    int ly = (int)(l >> 6), lx = (int)(l & 63);

    float* Sout = out;                       // [4,1,64,64]
    float* Uout = out + 16384;               // [4,1,64,64]
    float* Rout = out + 32768;               // [4,576,4096]
    float* Aout = out + 9469952;             // [4,4096] written as float values

    if (fq == 0) {
        float S = zero ? 1e-8f : fminf(fmaxf(val, 1e-8f), 1.0f);
        float U = zero ? 1e-8f : fminf(fmaxf(yprob[(size_t)n * LL + l], 1e-8f), 1.0f);
        Sout[(size_t)n * LL + m] = S;
        Uout[(size_t)n * LL + m] = U;
        Aout[(size_t)n * LL + m] = zero ? -1.0f : (float)l;
    }

    const float* src = yhat + (size_t)n * (Cc * LL);
    float* dst = Rout + (size_t)n * (576 * LL) + m;
    for (int f = fq; f < 576; f += 4) {
        int c = f / 9, ij = f % 9;
        int di = ij / 3 - 1, dj = ij % 3 - 1;
        int yy = ly + di, xx = lx + dj;
        float v = 0.f;
        if (!zero && yy >= 0 && yy < 64 && xx >= 0 && xx < 64)
            v = src[(size_t)c * LL + yy * 64 + xx];
        dst[(size_t)f * LL] = v;
    }
}

extern "C" void kernel_launch(void* const* d_in, const int* in_sizes, int n_in,
                              void* d_out, int out_size, void* d_ws, size_t ws_size,
                              hipStream_t stream) {
    const float* yhat  = (const float*)d_in[0];
    const float* yprob = (const float*)d_in[1];
    float* out = (float*)d_out;

    float* V = (float*)d_ws;                                    // 4*256*4096*4 = 16 MiB
    unsigned long long* best =
        (unsigned long long*)((char*)d_ws + (size_t)Nn * KK * LL * sizeof(float));

    hipMemsetAsync(best, 0, (size_t)Nn * LL * sizeof(unsigned long long), stream);
    build_v<<<(Nn * LL) / 256, 256, 0, stream>>>(yhat, V);
    simmax<<<Nn * TRI, 256, 0, stream>>>(V, best);
    writeout<<<Nn * 64, 256, 0, stream>>>(yhat, yprob, best, out);
}

// Round 4
// 165.942 us; speedup vs baseline: 2.2467x; 2.2467x over previous
//
#include <hip/hip_runtime.h>
#include <stdint.h>

// Problem constants
#define Nn 4
#define Cc 64
#define LL 4096   // H*W
#define KK 256    // feature dim: 64 channels * 4 causal taps
#define NB 32     // 4096/128 tiles per side
#define TRI2 528  // NB*(NB+1)/2 triangular 128x128 tile pairs per batch
#define PAD_H 40  // LDS row stride in halves (32 data + 8 pad = 80 B, 16B-aligned)

typedef _Float16 half8 __attribute__((ext_vector_type(8)));
typedef float f32x4 __attribute__((ext_vector_type(4)));

__device__ __forceinline__ unsigned f2ord(float f) {
    unsigned u = __float_as_uint(f);
    return u ^ ((u & 0x80000000u) ? 0xFFFFFFFFu : 0x80000000u);
}
__device__ __forceinline__ float ord2f(unsigned o) {
    unsigned u = (o & 0x80000000u) ? (o ^ 0x80000000u) : ~o;
    return __uint_as_float(u);
}
__device__ __forceinline__ unsigned short h2u(_Float16 h) {
    union { _Float16 f; unsigned short u; } x; x.f = h; return x.u;
}

// Kernel 1: build normalized masked context vectors, split into fp16 hi/lo.
// Layout: VhT/VlT[n][l][k], k = c*4+tap contiguous (256 halves = 512 B rows).
// lo is pre-scaled by 2048 so it stays in fp16 normal range.
__global__ __launch_bounds__(256) void build_v(const float* __restrict__ yhat,
                                               unsigned short* __restrict__ VhT,
                                               unsigned short* __restrict__ VlT) {
    int gid = blockIdx.x * 256 + threadIdx.x;
    int cg = gid & 7;            // channel group 0..7 (8 channels each)
    int nl = gid >> 3;           // n*4096 + l
    int n = nl >> 12;
    int l = nl & (LL - 1);
    int y = l >> 6, x = l & 63;
    const float* src = yhat + (size_t)n * (Cc * LL);

    float vals[32];
    float sumsq = 0.f;
#pragma unroll
    for (int ci = 0; ci < 8; ++ci) {
        const float* p = src + (cg * 8 + ci) * LL;
        float t0 = (y > 0 && x > 0)  ? p[l - 65] : 0.f;
        float t1 = (y > 0)           ? p[l - 64] : 0.f;
        float t2 = (y > 0 && x < 63) ? p[l - 63] : 0.f;
        float t3 = (x > 0)           ? p[l - 1]  : 0.f;
        vals[ci * 4 + 0] = t0; vals[ci * 4 + 1] = t1;
        vals[ci * 4 + 2] = t2; vals[ci * 4 + 3] = t3;
        sumsq += t0 * t0 + t1 * t1 + t2 * t2 + t3 * t3;
    }
    // reduce across the 8 lanes sharing this l (lane bits 0..2)
    sumsq += __shfl_xor(sumsq, 1, 64);
    sumsq += __shfl_xor(sumsq, 2, 64);
    sumsq += __shfl_xor(sumsq, 4, 64);
    float inv = 1.f / fmaxf(sqrtf(sumsq), 1e-12f);

    unsigned short* dh = VhT + (size_t)nl * KK + cg * 32;
    unsigned short* dl = VlT + (size_t)nl * KK + cg * 32;
#pragma unroll
    for (int ci = 0; ci < 8; ++ci) {
        ushort4 hv, lv;
        unsigned short* ph = &hv.x;
        unsigned short* pl = &lv.x;
#pragma unroll
        for (int tp = 0; tp < 4; ++tp) {
            float v = vals[ci * 4 + tp] * inv;
            _Float16 h = (fabsf(v) < 6.1035e-5f) ? (_Float16)0 : (_Float16)v;
            _Float16 lo = (_Float16)((v - (float)h) * 2048.0f);
            ph[tp] = h2u(h);
            pl[tp] = h2u(lo);
        }
        *(ushort4*)(dh + ci * 4) = hv;
        *(ushort4*)(dl + ci * 4) = lv;
    }
}

// Kernel 2: triangular 128x128-tiled similarity-max via split-fp16 MFMA.
// acc = 2048*h1*h2 + l1*h2 + h1*l2  (all scale 2048); val = acc/2048.
// Verified 16x16x32 layouts: A[m=lane&15][k=quad*8+j]; D: col=lane&15, row=quad*4+reg.
__global__ __launch_bounds__(256) void simmax(const unsigned short* __restrict__ Vh,
                                              const unsigned short* __restrict__ Vl,
                                              unsigned long long* __restrict__ best) {
    __shared__ __align__(16) unsigned short Ah[128 * PAD_H];
    __shared__ __align__(16) unsigned short Al[128 * PAD_H];
    __shared__ __align__(16) unsigned short Bh[128 * PAD_H];
    __shared__ __align__(16) unsigned short Bl[128 * PAD_H];

    int bx = blockIdx.x;
    int n = bx / TRI2;
    int t = bx % TRI2;
    int j = (int)((sqrtf(8.f * (float)t + 1.f) - 1.f) * 0.5f);
    while ((j + 1) * (j + 2) / 2 <= t) ++j;
    while (j * (j + 1) / 2 > t) --j;
    int i = t - j * (j + 1) / 2;
    int l0 = i * 128, m0 = j * 128;

    const unsigned short* VhB = Vh + (size_t)n * (LL * KK);
    const unsigned short* VlB = Vl + (size_t)n * (LL * KK);

    int tid = threadIdx.x;
    int w = tid >> 6, lane = tid & 63;
    int quad = lane >> 4, l16 = lane & 15;
    int rw = (w & 1) * 64;    // wave's row (l) quadrant
    int cw = (w >> 1) * 64;   // wave's col (m) quadrant
    // diagonal block, lower-left quadrant: entirely l>m -> skip compute (not staging)
    bool skip = (i == j) && (rw == 64) && (cw == 0);

    f32x4 acc[4][4];
#pragma unroll
    for (int r = 0; r < 4; ++r)
#pragma unroll
        for (int c = 0; c < 4; ++c) acc[r][c] = (f32x4)0.f;

    // Full-width staging: 128 rows x 32 halves per buffer per K-chunk.
    // 256 threads, 2 row-passes, 4 lanes x 8 halves per row.
    int srow = tid >> 2;          // 0..63
    int sh = (tid & 3) * 8;       // 0,8,16,24

    for (int k0 = 0; k0 < KK; k0 += 32) {
        const size_t ra = (size_t)(l0 + srow) * KK + k0 + sh;
        const size_t rb = (size_t)(l0 + 64 + srow) * KK + k0 + sh;
        const size_t rc = (size_t)(m0 + srow) * KK + k0 + sh;
        const size_t rd = (size_t)(m0 + 64 + srow) * KK + k0 + sh;
        uint4 ah0 = *(const uint4*)(VhB + ra);
        uint4 ah1 = *(const uint4*)(VhB + rb);
        uint4 al0 = *(const uint4*)(VlB + ra);
        uint4 al1 = *(const uint4*)(VlB + rb);
        uint4 bh0 = *(const uint4*)(VhB + rc);
        uint4 bh1 = *(const uint4*)(VhB + rd);
        uint4 bl0 = *(const uint4*)(VlB + rc);
        uint4 bl1 = *(const uint4*)(VlB + rd);
        __syncthreads();
        *(uint4*)&Ah[srow * PAD_H + sh]        = ah0;
        *(uint4*)&Ah[(64 + srow) * PAD_H + sh] = ah1;
        *(uint4*)&Al[srow * PAD_H + sh]        = al0;
        *(uint4*)&Al[(64 + srow) * PAD_H + sh] = al1;
        *(uint4*)&Bh[srow * PAD_H + sh]        = bh0;
        *(uint4*)&Bh[(64 + srow) * PAD_H + sh] = bh1;
        *(uint4*)&Bl[srow * PAD_H + sh]        = bl0;
        *(uint4*)&Bl[(64 + srow) * PAD_H + sh] = bl1;
        __syncthreads();
        if (!skip) {
            half8 ah[4], al[4], bh[4], bl[4];
#pragma unroll
            for (int r = 0; r < 4; ++r) {
                ah[r] = *(half8*)&Ah[(rw + r * 16 + l16) * PAD_H + quad * 8];
                al[r] = *(half8*)&Al[(rw + r * 16 + l16) * PAD_H + quad * 8];
                bh[r] = *(half8*)&Bh[(cw + r * 16 + l16) * PAD_H + quad * 8];
                bl[r] = *(half8*)&Bl[(cw + r * 16 + l16) * PAD_H + quad * 8];
            }
#pragma unroll
            for (int r = 0; r < 4; ++r)
#pragma unroll
                for (int c = 0; c < 4; ++c)
                    acc[r][c] = __builtin_amdgcn_mfma_f32_16x16x32_f16(al[r], bh[c], acc[r][c], 0, 0, 0);
#pragma unroll
            for (int r = 0; r < 4; ++r)
#pragma unroll
                for (int c = 0; c < 4; ++c)
                    acc[r][c] = __builtin_amdgcn_mfma_f32_16x16x32_f16(ah[r], bl[c], acc[r][c], 0, 0, 0);
            // scale h in place to 2048*h for the hh pass (exact pow2 scale)
#pragma unroll
            for (int r = 0; r < 4; ++r)
#pragma unroll
                for (int q = 0; q < 8; ++q) ah[r][q] = ah[r][q] * (_Float16)2048.0f;
#pragma unroll
            for (int r = 0; r < 4; ++r)
#pragma unroll
                for (int c = 0; c < 4; ++c)
                    acc[r][c] = __builtin_amdgcn_mfma_f32_16x16x32_f16(ah[r], bh[c], acc[r][c], 0, 0, 0);
        }
    }

    if (skip) return;
    unsigned long long* bb = best + (size_t)n * LL;
    const float s = 1.f / 2048.f;
#pragma unroll
    for (int c = 0; c < 4; ++c) {
        int m = m0 + cw + c * 16 + l16;
        unsigned long long key = 0ull;
#pragma unroll
        for (int r = 0; r < 4; ++r)
#pragma unroll
            for (int g = 0; g < 4; ++g) {
                int l = l0 + rw + r * 16 + quad * 4 + g;
                if (l < m) {
                    float v = acc[r][c][g] * s;
                    unsigned long long k2 =
                        ((unsigned long long)f2ord(v) << 32) |
                        (unsigned long long)(0xFFFFFFFFu - (unsigned)l);
                    key = (k2 > key) ? k2 : key;
                }
            }
        unsigned long long o1 = __shfl_xor(key, 16, 64); key = (o1 > key) ? o1 : key;
        unsigned long long o2 = __shfl_xor(key, 32, 64); key = (o2 > key) ? o2 : key;
        if (quad == 0 && key != 0ull) atomicMax(bb + m, key);
    }
}

// Kernel 3: unpack best, write S, U, ref_unfold, arg (as float values) with m==0 overrides.
// 4-way f-split across blocks for occupancy (1024 blocks).
__global__ __launch_bounds__(256) void writeout(const float* __restrict__ yhat,
                                                const float* __restrict__ yprob,
                                                const unsigned long long* __restrict__ best,
                                                float* __restrict__ out) {
    int bx = blockIdx.x;          // n*256 + mb*4 + fc
    int n = bx >> 8;
    int mb = (bx >> 2) & 63;
    int fc = bx & 3;
    int tid = threadIdx.x;
    int mm = tid & 63;
    int fs = tid >> 6;            // 0..3
    int m = mb * 64 + mm;

    unsigned long long key = best[(size_t)n * LL + m];
    unsigned l = 0xFFFFFFFFu - (unsigned)(key & 0xFFFFFFFFull);
    float val = ord2f((unsigned)(key >> 32));
    bool zero = (m == 0);
    if (zero) l = 0;
    int ly = (int)(l >> 6), lx = (int)(l & 63);

    float* Sout = out;                       // [4,1,64,64]
    float* Uout = out + 16384;               // [4,1,64,64]
    float* Rout = out + 32768;               // [4,576,4096]
    float* Aout = out + 9469952;             // [4,4096] as float values

    if (fc == 0 && fs == 0) {
        float S = zero ? 1e-8f : fminf(fmaxf(val, 1e-8f), 1.0f);
        float U = zero ? 1e-8f : fminf(fmaxf(yprob[(size_t)n * LL + l], 1e-8f), 1.0f);
        Sout[(size_t)n * LL + m] = S;
        Uout[(size_t)n * LL + m] = U;
        Aout[(size_t)n * LL + m] = zero ? -1.0f : (float)l;
    }

    const float* src = yhat + (size_t)n * (Cc * LL);
    float* dst = Rout + (size_t)n * (576 * LL) + m;
#pragma unroll 4
    for (int ii = 0; ii < 36; ++ii) {
        int f = fc * 144 + fs + 4 * ii;
        int c = f / 9, ij = f % 9;
        int di = ij / 3 - 1, dj = ij % 3 - 1;
        int yy = ly + di, xx = lx + dj;
        float v = 0.f;
        if (!zero && yy >= 0 && yy < 64 && xx >= 0 && xx < 64)
            v = src[(size_t)c * LL + yy * 64 + xx];
        dst[(size_t)f * LL] = v;
    }
}

extern "C" void kernel_launch(void* const* d_in, const int* in_sizes, int n_in,
                              void* d_out, int out_size, void* d_ws, size_t ws_size,
                              hipStream_t stream) {
    const float* yhat  = (const float*)d_in[0];
    const float* yprob = (const float*)d_in[1];
    float* out = (float*)d_out;

    unsigned short* VhT = (unsigned short*)d_ws;                       // 8 MiB
    unsigned short* VlT = (unsigned short*)((char*)d_ws + 8388608);    // 8 MiB
    unsigned long long* best =
        (unsigned long long*)((char*)d_ws + 16777216);                 // 128 KiB

    hipMemsetAsync(best, 0, (size_t)Nn * LL * sizeof(unsigned long long), stream);
    build_v<<<512, 256, 0, stream>>>(yhat, VhT, VlT);
    simmax<<<Nn * TRI2, 256, 0, stream>>>(VhT, VlT, best);
    writeout<<<Nn * 64 * 4, 256, 0, stream>>>(yhat, yprob, best, out);
}

// Round 5
// 162.781 us; speedup vs baseline: 2.2904x; 1.0194x over previous
//
#include <hip/hip_runtime.h>
#include <stdint.h>

// Problem constants
#define Nn 4
#define Cc 64
#define LL 4096   // H*W
#define KK 256    // feature dim: 64 channels * 4 causal taps
#define NB 32     // 4096/128 tiles per side
#define TRI2 528  // NB*(NB+1)/2 triangular 128x128 tile pairs per batch
#define PAD_H 40  // LDS row stride in halves (32 data + 8 pad = 80 B, 16B-aligned)

typedef _Float16 half8 __attribute__((ext_vector_type(8)));
typedef float f32x16 __attribute__((ext_vector_type(16)));
typedef float f4a __attribute__((ext_vector_type(4), aligned(4)));  // 4B-aligned float4

__device__ __forceinline__ unsigned f2ord(float f) {
    unsigned u = __float_as_uint(f);
    return u ^ ((u & 0x80000000u) ? 0xFFFFFFFFu : 0x80000000u);
}
__device__ __forceinline__ float ord2f(unsigned o) {
    unsigned u = (o & 0x80000000u) ? (o ^ 0x80000000u) : ~o;
    return __uint_as_float(u);
}
__device__ __forceinline__ unsigned short h2u(_Float16 h) {
    union { _Float16 f; unsigned short u; } x; x.f = h; return x.u;
}

// Kernel 1: normalized masked context vectors, split fp16 hi/lo, both pre-scaled:
//   Vh' = 2048*fp16(v)  (exact pow2),  Vl = fp16((v - fp16(v)) * 2048)
// so  2^22 * v1*v2 ~= Vh1'*Vh2' + Vh1'*Vl2 + Vl1*Vh2'  (one scale, no repack in GEMM).
// Layout: [n][l][k], k = c*4+tap contiguous. 16 lanes cooperate per l (4 channels each).
__global__ __launch_bounds__(256) void build_v(const float* __restrict__ yhat,
                                               unsigned short* __restrict__ VhT,
                                               unsigned short* __restrict__ VlT) {
    int gid = blockIdx.x * 256 + threadIdx.x;
    int cg = gid & 15;           // channel group 0..15 (4 channels each)
    int nl = gid >> 4;           // n*4096 + l
    int l = nl & (LL - 1);
    int n = nl >> 12;
    int y = l >> 6, x = l & 63;
    const float* src = yhat + (size_t)n * (Cc * LL);

    float vals[16];
    float sumsq = 0.f;
#pragma unroll
    for (int ci = 0; ci < 4; ++ci) {
        const float* p = src + (cg * 4 + ci) * LL;
        float t0 = (y > 0 && x > 0)  ? p[l - 65] : 0.f;
        float t1 = (y > 0)           ? p[l - 64] : 0.f;
        float t2 = (y > 0 && x < 63) ? p[l - 63] : 0.f;
        float t3 = (x > 0)           ? p[l - 1]  : 0.f;
        vals[ci * 4 + 0] = t0; vals[ci * 4 + 1] = t1;
        vals[ci * 4 + 2] = t2; vals[ci * 4 + 3] = t3;
        sumsq += t0 * t0 + t1 * t1 + t2 * t2 + t3 * t3;
    }
    // reduce across the 16 lanes sharing this l (lane bits 0..3)
    sumsq += __shfl_xor(sumsq, 1, 64);
    sumsq += __shfl_xor(sumsq, 2, 64);
    sumsq += __shfl_xor(sumsq, 4, 64);
    sumsq += __shfl_xor(sumsq, 8, 64);
    float inv = 1.f / fmaxf(sqrtf(sumsq), 1e-12f);

    unsigned short* dh = VhT + (size_t)nl * KK + cg * 16;
    unsigned short* dl = VlT + (size_t)nl * KK + cg * 16;
#pragma unroll
    for (int ci = 0; ci < 4; ++ci) {
        ushort4 hv, lv;
        unsigned short* ph = &hv.x;
        unsigned short* pl = &lv.x;
#pragma unroll
        for (int tp = 0; tp < 4; ++tp) {
            float v = vals[ci * 4 + tp] * inv;
            _Float16 h = (fabsf(v) < 6.1035e-5f) ? (_Float16)0 : (_Float16)v;
            _Float16 lo = (_Float16)((v - (float)h) * 2048.0f);
            ph[tp] = h2u(h * (_Float16)2048.0f);   // exact
            pl[tp] = h2u(lo);
        }
        *(ushort4*)(dh + ci * 4) = hv;
        *(ushort4*)(dl + ci * 4) = lv;
    }
}

// Kernel 2: triangular 128x128-tiled similarity-max via split-fp16 32x32x16 MFMA.
// acc = Vh1'Vh2' + Vh1'Vl2 + Vl1Vh2' = 2^22 * v1.v2 ; val = acc * 2^-22.
// 32x32x16 layouts: A/B row(col)=lane&31, k=(lane>>5)*8+j;
// C/D: col=lane&31, row=(reg&3)+8*(reg>>2)+4*(lane>>5)  [guide-verified].
__global__ __launch_bounds__(256) void simmax(const unsigned short* __restrict__ Vh,
                                              const unsigned short* __restrict__ Vl,
                                              unsigned long long* __restrict__ best) {
    __shared__ __align__(16) unsigned short Ah[128 * PAD_H];
    __shared__ __align__(16) unsigned short Al[128 * PAD_H];
    __shared__ __align__(16) unsigned short Bh[128 * PAD_H];
    __shared__ __align__(16) unsigned short Bl[128 * PAD_H];

    // XCD swizzle: blocks dispatch round-robin by blockIdx%8; pin each XCD to one
    // batch-half so its 4MB L2 holds that batch's V (4MB) -> fewer HBM refetches.
    int bx = blockIdx.x;              // 0..2111
    int xcd = bx & 7, idx = bx >> 3;  // idx 0..263
    int n = xcd >> 1;
    int t = (xcd & 1) * 264 + idx;    // 0..527
    int j = (int)((sqrtf(8.f * (float)t + 1.f) - 1.f) * 0.5f);
    while ((j + 1) * (j + 2) / 2 <= t) ++j;
    while (j * (j + 1) / 2 > t) --j;
    int i = t - j * (j + 1) / 2;
    int l0 = i * 128, m0 = j * 128;

    const unsigned short* VhB = Vh + (size_t)n * (LL * KK);
    const unsigned short* VlB = Vl + (size_t)n * (LL * KK);

    int tid = threadIdx.x;
    int w = tid >> 6, lane = tid & 63;
    int r5 = lane & 31, h5 = lane >> 5;
    int rw = (w & 1) * 64;    // wave's row (l) quadrant
    int cw = (w >> 1) * 64;   // wave's col (m) quadrant
    bool skip = (i == j) && (rw == 64) && (cw == 0);  // fully l>m

    f32x16 acc[2][2];
#pragma unroll
    for (int r = 0; r < 2; ++r)
#pragma unroll
        for (int c = 0; c < 2; ++c) acc[r][c] = (f32x16)0.f;

    // Full-width staging: 128 rows x 32 halves per buffer per K-chunk.
    int srow = tid >> 2;          // 0..63
    int sh = (tid & 3) * 8;       // 0,8,16,24

    for (int k0 = 0; k0 < KK; k0 += 32) {
        const size_t ra = (size_t)(l0 + srow) * KK + k0 + sh;
        const size_t rb = (size_t)(l0 + 64 + srow) * KK + k0 + sh;
        const size_t rc = (size_t)(m0 + srow) * KK + k0 + sh;
        const size_t rd = (size_t)(m0 + 64 + srow) * KK + k0 + sh;
        uint4 ah0 = *(const uint4*)(VhB + ra);
        uint4 ah1 = *(const uint4*)(VhB + rb);
        uint4 al0 = *(const uint4*)(VlB + ra);
        uint4 al1 = *(const uint4*)(VlB + rb);
        uint4 bh0 = *(const uint4*)(VhB + rc);
        uint4 bh1 = *(const uint4*)(VhB + rd);
        uint4 bl0 = *(const uint4*)(VlB + rc);
        uint4 bl1 = *(const uint4*)(VlB + rd);
        __syncthreads();
        *(uint4*)&Ah[srow * PAD_H + sh]        = ah0;
        *(uint4*)&Ah[(64 + srow) * PAD_H + sh] = ah1;
        *(uint4*)&Al[srow * PAD_H + sh]        = al0;
        *(uint4*)&Al[(64 + srow) * PAD_H + sh] = al1;
        *(uint4*)&Bh[srow * PAD_H + sh]        = bh0;
        *(uint4*)&Bh[(64 + srow) * PAD_H + sh] = bh1;
        *(uint4*)&Bl[srow * PAD_H + sh]        = bl0;
        *(uint4*)&Bl[(64 + srow) * PAD_H + sh] = bl1;
        __syncthreads();
        if (!skip) {
            half8 fah[2][2], fal[2][2], fbh[2][2], fbl[2][2];
#pragma unroll
            for (int r = 0; r < 2; ++r)
#pragma unroll
                for (int kc = 0; kc < 2; ++kc) {
                    int ao = (rw + r * 32 + r5) * PAD_H + kc * 16 + h5 * 8;
                    int bo = (cw + r * 32 + r5) * PAD_H + kc * 16 + h5 * 8;
                    fah[r][kc] = *(half8*)&Ah[ao];
                    fal[r][kc] = *(half8*)&Al[ao];
                    fbh[r][kc] = *(half8*)&Bh[bo];
                    fbl[r][kc] = *(half8*)&Bl[bo];
                }
#pragma unroll
            for (int kc = 0; kc < 2; ++kc)
#pragma unroll
                for (int r = 0; r < 2; ++r)
#pragma unroll
                    for (int c = 0; c < 2; ++c)
                        acc[r][c] = __builtin_amdgcn_mfma_f32_32x32x16_f16(fal[r][kc], fbh[c][kc], acc[r][c], 0, 0, 0);
#pragma unroll
            for (int kc = 0; kc < 2; ++kc)
#pragma unroll
                for (int r = 0; r < 2; ++r)
#pragma unroll
                    for (int c = 0; c < 2; ++c)
                        acc[r][c] = __builtin_amdgcn_mfma_f32_32x32x16_f16(fah[r][kc], fbl[c][kc], acc[r][c], 0, 0, 0);
#pragma unroll
            for (int kc = 0; kc < 2; ++kc)
#pragma unroll
                for (int r = 0; r < 2; ++r)
#pragma unroll
                    for (int c = 0; c < 2; ++c)
                        acc[r][c] = __builtin_amdgcn_mfma_f32_32x32x16_f16(fah[r][kc], fbh[c][kc], acc[r][c], 0, 0, 0);
        }
    }

    if (skip) return;
    unsigned long long* bb = best + (size_t)n * LL;
    const float s = 1.f / 4194304.f;   // 2^-22
#pragma unroll
    for (int c = 0; c < 2; ++c) {
        int m = m0 + cw + c * 32 + r5;
        unsigned long long key = 0ull;
#pragma unroll
        for (int r = 0; r < 2; ++r)
#pragma unroll
            for (int g = 0; g < 16; ++g) {
                int l = l0 + rw + r * 32 + (g & 3) + 8 * (g >> 2) + 4 * h5;
                if (l < m) {
                    float v = acc[r][c][g] * s;
                    unsigned long long k2 =
                        ((unsigned long long)f2ord(v) << 32) |
                        (unsigned long long)(0xFFFFFFFFu - (unsigned)l);
                    key = (k2 > key) ? k2 : key;
                }
            }
        unsigned long long o = __shfl_xor(key, 32, 64);
        key = (o > key) ? o : key;
        if (h5 == 0 && key != 0ull) atomicMax(bb + m, key);
    }
}

// Kernel 3: unpack best, write S, U, ref_unfold, arg (float values), m==0 overrides.
// Each thread: 4 channels x 3 rows via unaligned float4 gathers (3 taps per load).
__global__ __launch_bounds__(256) void writeout(const float* __restrict__ yhat,
                                                const float* __restrict__ yprob,
                                                const unsigned long long* __restrict__ best,
                                                float* __restrict__ out) {
    int bx = blockIdx.x;          // n*256 + mb*4 + fc
    int n = bx >> 8;
    int mb = (bx >> 2) & 63;
    int fc = bx & 3;              // channel quarter (16 channels)
    int tid = threadIdx.x;
    int mm = tid & 63;
    int fs = tid >> 6;            // 0..3 -> 4 channels each
    int m = mb * 64 + mm;

    unsigned long long key = best[(size_t)n * LL + m];
    unsigned l = 0xFFFFFFFFu - (unsigned)(key & 0xFFFFFFFFull);
    float val = ord2f((unsigned)(key >> 32));
    bool zero = (m == 0);
    if (zero) l = 0;
    int ly = (int)(l >> 6), lx = (int)(l & 63);

    float* Sout = out;                       // [4,1,64,64]
    float* Uout = out + 16384;               // [4,1,64,64]
    float* Rout = out + 32768;               // [4,576,4096]
    float* Aout = out + 9469952;             // [4,4096] as float values

    if (fc == 0 && fs == 0) {
        float S = zero ? 1e-8f : fminf(fmaxf(val, 1e-8f), 1.0f);
        float U = zero ? 1e-8f : fminf(fmaxf(yprob[(size_t)n * LL + l], 1e-8f), 1.0f);
        Sout[(size_t)n * LL + m] = S;
        Uout[(size_t)n * LL + m] = U;
        Aout[(size_t)n * LL + m] = zero ? -1.0f : (float)l;
    }

    const float* src = yhat + (size_t)n * (Cc * LL);
    float* dst = Rout + (size_t)n * (576 * LL) + m;
    bool fast = (!zero) && (lx >= 1) && (lx <= 61);
#pragma unroll
    for (int cc = 0; cc < 4; ++cc) {
        int c = fc * 16 + fs * 4 + cc;
        const float* plane = src + (size_t)c * LL;
#pragma unroll
        for (int r3 = 0; r3 < 3; ++r3) {
            int yy = ly + r3 - 1;
            bool rowok = (!zero) && (yy >= 0) && (yy < 64);
            float t0 = 0.f, t1 = 0.f, t2 = 0.f;
            if (rowok) {
                if (fast) {
                    f4a v = *(const f4a*)(plane + yy * 64 + lx - 1);
                    t0 = v.x; t1 = v.y; t2 = v.z;
                } else {
                    if (lx > 0)  t0 = plane[yy * 64 + lx - 1];
                    t1 = plane[yy * 64 + lx];
                    if (lx < 63) t2 = plane[yy * 64 + lx + 1];
                }
            }
            size_t f = (size_t)(c * 9 + r3 * 3) * LL;
            __builtin_nontemporal_store(t0, dst + f);
            __builtin_nontemporal_store(t1, dst + f + LL);
            __builtin_nontemporal_store(t2, dst + f + 2 * (size_t)LL);
        }
    }
}

extern "C" void kernel_launch(void* const* d_in, const int* in_sizes, int n_in,
                              void* d_out, int out_size, void* d_ws, size_t ws_size,
                              hipStream_t stream) {
    const float* yhat  = (const float*)d_in[0];
    const float* yprob = (const float*)d_in[1];
    float* out = (float*)d_out;

    unsigned short* VhT = (unsigned short*)d_ws;                       // 8 MiB
    unsigned short* VlT = (unsigned short*)((char*)d_ws + 8388608);    // 8 MiB
    unsigned long long* best =
        (unsigned long long*)((char*)d_ws + 16777216);                 // 128 KiB

    hipMemsetAsync(best, 0, (size_t)Nn * LL * sizeof(unsigned long long), stream);
    build_v<<<1024, 256, 0, stream>>>(yhat, VhT, VlT);
    simmax<<<Nn * TRI2, 256, 0, stream>>>(VhT, VlT, best);
    writeout<<<Nn * 64 * 4, 256, 0, stream>>>(yhat, yprob, best, out);
}